// Round 1
// baseline (1001.072 us; speedup 1.0000x reference)
//
#include <hip/hip_runtime.h>

typedef unsigned short u16;
typedef short bf16x8 __attribute__((ext_vector_type(8)));
typedef u16 u16x8 __attribute__((ext_vector_type(8)));
typedef float f32x4 __attribute__((ext_vector_type(4)));

__device__ __forceinline__ float bf2f(u16 u) {
    union { unsigned u; float f; } c; c.u = ((unsigned)u) << 16; return c.f;
}
__device__ __forceinline__ u16 f2bf(float f) {
    union { float f; unsigned u; } c; c.f = f;
    unsigned r = c.u + 0x7FFFu + ((c.u >> 16) & 1u);
    return (u16)(r >> 16);
}
// tanh(x) = 1 - 2/(e^{2x}+1): no NaN at large |x| (inf -> 1, 0 -> -1)
__device__ __forceinline__ float tanh_fast(float x) {
    float e = __expf(2.0f * x);
    return 1.0f - 2.0f / (e + 1.0f);
}
__device__ __forceinline__ void gll16(const void* g, void* l) {
    __builtin_amdgcn_global_load_lds((const __attribute__((address_space(1))) void*)g,
                                     (__attribute__((address_space(3))) void*)l, 16, 0, 0);
}

// ---------------- f32 -> bf16 convert, 8 elems/thread ----------------
__global__ __launch_bounds__(256) void cvt_f32_bf16(const float* __restrict__ src,
                                                    u16* __restrict__ dst, int n8) {
    int i = blockIdx.x * blockDim.x + threadIdx.x;
    int stride = gridDim.x * blockDim.x;
    for (; i < n8; i += stride) {
        const float4* s = (const float4*)(src + (size_t)i * 8);
        float4 a = s[0], b = s[1];
        u16x8 o;
        o[0] = f2bf(a.x); o[1] = f2bf(a.y); o[2] = f2bf(a.z); o[3] = f2bf(a.w);
        o[4] = f2bf(b.x); o[5] = f2bf(b.y); o[6] = f2bf(b.z); o[7] = f2bf(b.w);
        *(u16x8*)(dst + (size_t)i * 8) = o;
    }
}

// ---------------- mq = tanh(Wm @ m_q + bm), one wave per output ----------------
__global__ __launch_bounds__(256) void mq_kernel(const float* __restrict__ Wm,
                                                 const float* __restrict__ q,
                                                 const float* __restrict__ bm,
                                                 float* __restrict__ mq, int D) {
    int w = threadIdx.x >> 6, l = threadIdx.x & 63;
    int e = blockIdx.x * 4 + w;
    const float* wp = Wm + (size_t)e * D;
    float s = 0.f;
    for (int j = 0; j < D; j += 256) {
        float4 wv = *(const float4*)(wp + j + l * 4);
        float4 qv = *(const float4*)(q + j + l * 4);
        s += wv.x * qv.x + wv.y * qv.y + wv.z * qv.z + wv.w * qv.w;
    }
    #pragma unroll
    for (int o = 32; o >= 1; o >>= 1) s += __shfl_xor(s, o);
    if (l == 0) mq[e] = tanh_fast(s + bm[e]);
}

// ---------------- C[M,N] = A[M,K] @ B[N,K]^T, bf16 in, bf16 out ----------------
// 128x128 tile, BK=32, 4 waves (2x2), 16x16x32 MFMA, global_load_lds staging.
// EPI=0: C = bf16( tanh(acc + bias[col]) * gate[col] )   (GEMM1 -> Sg)
// EPI=1: C = bf16( acc + bias[col] )                      (GEMM2 -> logits)
template <int EPI>
__global__ __launch_bounds__(256) void gemm_bt(const u16* __restrict__ A,
                                               const u16* __restrict__ B,
                                               const float* __restrict__ bias,
                                               const float* __restrict__ gate,
                                               u16* __restrict__ C,
                                               int M, int N, int K) {
    __shared__ u16 lda[128 * 32];
    __shared__ u16 ldb[128 * 32];
    const int tid = threadIdx.x;
    const int w = tid >> 6;
    const int l = tid & 63;
    const int wm = w >> 1, wn = w & 1;
    const int tileM = blockIdx.y * 128;
    const int tileN = blockIdx.x * 128;

    // staging: wave w covers rows 32w..32w+31 (two 1KB calls of 16 rows each)
    const int srow = 32 * w + (l >> 2);
    const int scol = (l & 3) * 8;
    const u16* ag0 = A + (size_t)(tileM + srow) * K + scol;
    const u16* ag1 = ag0 + (size_t)16 * K;
    const u16* bg0 = B + (size_t)(tileN + srow) * K + scol;
    const u16* bg1 = bg0 + (size_t)16 * K;
    u16* la = lda + w * 1024;   // wave-uniform LDS base (2048 B per wave)
    u16* lb = ldb + w * 1024;

    f32x4 acc[4][4] = {};

    // fragment read offsets (elements): row-major [128][32] tile
    const int aoff = (wm * 64 + (l & 15)) * 32 + (l >> 4) * 8;
    const int boff = (wn * 64 + (l & 15)) * 32 + (l >> 4) * 8;

    for (int k0 = 0; k0 < K; k0 += 32) {
        __syncthreads();
        gll16(ag0 + k0, la);
        gll16(ag1 + k0, la + 512);
        gll16(bg0 + k0, lb);
        gll16(bg1 + k0, lb + 512);
        __syncthreads();
        bf16x8 af[4], bf[4];
        #pragma unroll
        for (int i = 0; i < 4; ++i) af[i] = *(const bf16x8*)&lda[aoff + i * 16 * 32];
        #pragma unroll
        for (int i = 0; i < 4; ++i) bf[i] = *(const bf16x8*)&ldb[boff + i * 16 * 32];
        #pragma unroll
        for (int mi = 0; mi < 4; ++mi)
            #pragma unroll
            for (int ni = 0; ni < 4; ++ni)
                acc[mi][ni] = __builtin_amdgcn_mfma_f32_16x16x32_bf16(af[mi], bf[ni], acc[mi][ni], 0, 0, 0);
    }

    // epilogue: C/D layout col = lane&15, row = (lane>>4)*4 + reg
    #pragma unroll
    for (int mi = 0; mi < 4; ++mi) {
        #pragma unroll
        for (int r = 0; r < 4; ++r) {
            int row = tileM + wm * 64 + mi * 16 + (l >> 4) * 4 + r;
            #pragma unroll
            for (int ni = 0; ni < 4; ++ni) {
                int col = tileN + wn * 64 + ni * 16 + (l & 15);
                float v = acc[mi][ni][r] + bias[col];
                if (EPI == 0) v = tanh_fast(v) * gate[col];
                C[(size_t)row * N + col] = f2bf(v);
            }
        }
    }
}

// ---------------- row softmax + weighted sum + m_q_new ----------------
// One block (256 thr) per row: 2048 logits (bf16) + 2048 hidden (f32).
__global__ __launch_bounds__(256) void softmax_out(const u16* __restrict__ logits,
                                                   const float* __restrict__ hidden,
                                                   const float* __restrict__ m_q,
                                                   float* __restrict__ out,
                                                   int D, int R) {
    const int r = blockIdx.x;
    const int t = threadIdx.x;
    const int w = t >> 6, l = t & 63;
    const u16* lp = logits + (size_t)r * D + t * 8;
    const float* hp = hidden + (size_t)r * D + t * 8;

    bf16x8 lv = *(const bf16x8*)lp;
    float lf[8];
    #pragma unroll
    for (int j = 0; j < 8; ++j) lf[j] = bf2f((u16)lv[j]);
    float4 h0 = *(const float4*)hp;
    float4 h1 = *(const float4*)(hp + 4);
    float hv[8] = {h0.x, h0.y, h0.z, h0.w, h1.x, h1.y, h1.z, h1.w};

    float m = lf[0];
    #pragma unroll
    for (int j = 1; j < 8; ++j) m = fmaxf(m, lf[j]);
    #pragma unroll
    for (int o = 32; o >= 1; o >>= 1) m = fmaxf(m, __shfl_xor(m, o));

    __shared__ float red[8];
    if (l == 0) red[w] = m;
    __syncthreads();
    m = fmaxf(fmaxf(red[0], red[1]), fmaxf(red[2], red[3]));
    __syncthreads();

    float se = 0.f, sh = 0.f;
    #pragma unroll
    for (int j = 0; j < 8; ++j) {
        float e = __expf(lf[j] - m);
        se += e;
        sh += e * hv[j];
    }
    #pragma unroll
    for (int o = 32; o >= 1; o >>= 1) { se += __shfl_xor(se, o); sh += __shfl_xor(sh, o); }
    if (l == 0) { red[w] = se; red[4 + w] = sh; }
    __syncthreads();
    if (t == 0) {
        float SE = red[0] + red[1] + red[2] + red[3];
        float SH = red[4] + red[5] + red[6] + red[7];
        float o = SH / SE;
        out[r] = o;                            // output[b,s]
        out[R + r] = m_q[r & (D - 1)] + o;     // m_q_new[b,s] = m_q[s] + output
    }
}

extern "C" void kernel_launch(void* const* d_in, const int* in_sizes, int n_in,
                              void* d_out, int out_size, void* d_ws, size_t ws_size,
                              hipStream_t stream) {
    const float* hidden = (const float*)d_in[0];
    const float* m_q    = (const float*)d_in[1];
    const float* Wq     = (const float*)d_in[2];
    const float* bq     = (const float*)d_in[3];
    const float* Wm     = (const float*)d_in[4];
    const float* bm     = (const float*)d_in[5];
    const float* Wa     = (const float*)d_in[6];
    const float* ba     = (const float*)d_in[7];
    float* out = (float*)d_out;

    const int D = 2048;
    const int M = 16 * 2048;  // B*S = 32768

    // ws layout (logits aliases hidden_bf16 — dead after GEMM1)
    char* ws = (char*)d_ws;
    size_t oH  = 0;
    size_t oS  = oH  + (size_t)M * D * 2;   // Sg bf16
    size_t oWq = oS  + (size_t)M * D * 2;
    size_t oWa = oWq + (size_t)D * D * 2;
    size_t oMq = oWa + (size_t)D * D * 2;
    size_t need = oMq + (size_t)D * sizeof(float);
    if (ws_size < need) return;  // ws too small: bench will show stub-like absmax

    u16* hbf    = (u16*)(ws + oH);
    u16* Sg     = (u16*)(ws + oS);
    u16* Wqb    = (u16*)(ws + oWq);
    u16* Wab    = (u16*)(ws + oWa);
    float* mq   = (float*)(ws + oMq);
    u16* logits = hbf;  // alias

    cvt_f32_bf16<<<4096, 256, 0, stream>>>(hidden, hbf, M * D / 8);
    cvt_f32_bf16<<<1024, 256, 0, stream>>>(Wq, Wqb, D * D / 8);
    cvt_f32_bf16<<<1024, 256, 0, stream>>>(Wa, Wab, D * D / 8);
    mq_kernel<<<D / 4, 256, 0, stream>>>(Wm, m_q, bm, mq, D);

    dim3 grid(D / 128, M / 128);  // (16, 256)
    gemm_bt<0><<<grid, 256, 0, stream>>>(hbf, Wqb, bq, mq, Sg, M, D, D);
    gemm_bt<1><<<grid, 256, 0, stream>>>(Sg, Wab, ba, nullptr, logits, M, D, D);

    softmax_out<<<M, 256, 0, stream>>>(logits, hidden, m_q, out, D, M);
}

// Round 2
// 710.751 us; speedup vs baseline: 1.4085x; 1.4085x over previous
//
#include <hip/hip_runtime.h>

typedef unsigned short u16;
typedef short bf16x8 __attribute__((ext_vector_type(8)));
typedef u16 u16x8 __attribute__((ext_vector_type(8)));
typedef float f32x4 __attribute__((ext_vector_type(4)));

__device__ __forceinline__ float bf2f(u16 u) {
    union { unsigned u; float f; } c; c.u = ((unsigned)u) << 16; return c.f;
}
__device__ __forceinline__ u16 f2bf(float f) {
    union { float f; unsigned u; } c; c.f = f;
    unsigned r = c.u + 0x7FFFu + ((c.u >> 16) & 1u);
    return (u16)(r >> 16);
}
__device__ __forceinline__ float tanh_fast(float x) {
    float e = __expf(2.0f * x);
    return 1.0f - 2.0f / (e + 1.0f);
}
__device__ __forceinline__ void gll16(const void* g, void* l) {
    __builtin_amdgcn_global_load_lds((const __attribute__((address_space(1))) void*)g,
                                     (__attribute__((address_space(3))) void*)l, 16, 0, 0);
}

#define BAR() do { __builtin_amdgcn_sched_barrier(0); __builtin_amdgcn_s_barrier(); \
                   __builtin_amdgcn_sched_barrier(0); } while (0)

// ---------------- f32 -> bf16 convert, 8 elems/thread ----------------
__global__ __launch_bounds__(256) void cvt_f32_bf16(const float* __restrict__ src,
                                                    u16* __restrict__ dst, int n8) {
    int i = blockIdx.x * blockDim.x + threadIdx.x;
    int stride = gridDim.x * blockDim.x;
    for (; i < n8; i += stride) {
        const float4* s = (const float4*)(src + (size_t)i * 8);
        float4 a = s[0], b = s[1];
        u16x8 o;
        o[0] = f2bf(a.x); o[1] = f2bf(a.y); o[2] = f2bf(a.z); o[3] = f2bf(a.w);
        o[4] = f2bf(b.x); o[5] = f2bf(b.y); o[6] = f2bf(b.z); o[7] = f2bf(b.w);
        *(u16x8*)(dst + (size_t)i * 8) = o;
    }
}

// ---------------- mq = tanh(Wm @ m_q + bm), one wave per output ----------------
__global__ __launch_bounds__(256) void mq_kernel(const float* __restrict__ Wm,
                                                 const float* __restrict__ q,
                                                 const float* __restrict__ bm,
                                                 float* __restrict__ mq, int D) {
    int w = threadIdx.x >> 6, l = threadIdx.x & 63;
    int e = blockIdx.x * 4 + w;
    const float* wp = Wm + (size_t)e * D;
    float s = 0.f;
    for (int j = 0; j < D; j += 256) {
        float4 wv = *(const float4*)(wp + j + l * 4);
        float4 qv = *(const float4*)(q + j + l * 4);
        s += wv.x * qv.x + wv.y * qv.y + wv.z * qv.z + wv.w * qv.w;
    }
    #pragma unroll
    for (int o = 32; o >= 1; o >>= 1) s += __shfl_xor(s, o);
    if (l == 0) mq[e] = tanh_fast(s + bm[e]);
}

// ---------------- C[M,N] = A[M,K] @ B[N,K]^T : 256x256 8-phase template ----------------
// 8 waves (2M x 4N, interleaved quadrants), BK=64, st_16x32 LDS swizzle,
// counted vmcnt(4) per K-tile, setprio around MFMA clusters.
// EPI=0: C = bf16( tanh(acc+bias[col]) * gate[col] );  EPI=1: C = bf16(acc+bias[col])
template <int EPI>
__global__ __launch_bounds__(512, 2) void gemm8(const u16* __restrict__ A,
                                                const u16* __restrict__ B,
                                                const float* __restrict__ bias,
                                                const float* __restrict__ gate,
                                                u16* __restrict__ C,
                                                int M, int N, int K) {
    __shared__ u16 sh[65536];            // 128 KiB: A half-slots [4x16KB] | B half-slots [4x16KB]
    char* LDS = (char*)sh;
    const int K2 = K * 2;
    const int KT = K >> 6;               // K-tiles of 64

    const int tid = threadIdx.x;
    const int w = tid >> 6, l = tid & 63;
    const int wm = w >> 2, wn = w & 3;

    // XCD-aware swizzle (nwg = 1024, divisible by 8)
    int orig = blockIdx.x + gridDim.x * blockIdx.y;
    int nwg = gridDim.x * gridDim.y;
    int id = ((nwg & 7) == 0) ? ((orig & 7) * (nwg >> 3) + (orig >> 3)) : orig;
    const int tileN = (id % gridDim.x) * 256;
    const int tileM = (id / gridDim.x) * 256;

    // ---- staging geometry (pre-swizzled global source, linear LDS dest) ----
    // lane writes LDS byte b = wj*1024 + l*16 ; logical byte = b ^ ((b>>9&1)<<5)
    //  -> row = wj*8 + (l>>3) ; colbyte = ((l&7)<<4) ^ (l&32)
    const int r0 = (w * 2) * 8 + (l >> 3);
    const int r1 = (w * 2 + 1) * 8 + (l >> 3);
    const int cc = ((l & 7) << 4) ^ (l & 32);
    const char* srcA0 = (const char*)A + (size_t)(tileM + r0) * K2 + cc;
    const char* srcA1 = (const char*)A + (size_t)(tileM + r1) * K2 + cc;
    const char* srcB0 = (const char*)B + (size_t)(tileN + r0) * K2 + cc;
    const char* srcB1 = (const char*)B + (size_t)(tileN + r1) * K2 + cc;
    const int ldc0 = (w * 2) * 1024, ldc1 = (w * 2 + 1) * 1024;

#define STG_A(tk, h) do { size_t go = (size_t)(tk) * 128 + (size_t)(h) * 128 * K2; \
    int sb = ((((tk) & 1) * 2 + (h)) * 16384); \
    gll16(srcA0 + go, LDS + sb + ldc0); gll16(srcA1 + go, LDS + sb + ldc1); } while (0)
#define STG_B(tk, h) do { size_t go = (size_t)(tk) * 128 + (size_t)(h) * 128 * K2; \
    int sb = 65536 + ((((tk) & 1) * 2 + (h)) * 16384); \
    gll16(srcB0 + go, LDS + sb + ldc0); gll16(srcB1 + go, LDS + sb + ldc1); } while (0)

    // ---- reader geometry (swizzled ds_read: XOR bit5 with row bit2 = l&4) ----
    const int rowA = (wm * 64 + (l & 15)) * 128;
    const int rowB = (wn * 32 + (l & 15)) * 128;
    const int ck0 = (((l >> 4) << 4)) ^ ((l & 4) << 3);
    const int ck1 = (64 + ((l >> 4) << 4)) ^ ((l & 4) << 3);

    f32x4 acc[2][4][2][2] = {};

    // ---- prologue: tile0 all 4 halves + tile1 A0,B0 ----
    STG_A(0, 0); STG_A(0, 1); STG_B(0, 0); STG_B(0, 1);
    STG_A(1, 0); STG_B(1, 0);
    asm volatile("s_waitcnt vmcnt(4)" ::: "memory");   // tile0 landed, 2 halves in flight
    BAR();

    for (int t = 0; t < KT; ++t) {
        const int p = t & 1;
        const int aS0 = (p * 2) * 16384, aS1 = (p * 2 + 1) * 16384;
        const int bS0 = 65536 + (p * 2) * 16384, bS1 = 65536 + (p * 2 + 1) * 16384;
        bf16x8 af[4][2], b0[2][2], b1[2][2];

        // ---- phase 1: quadrant (0,0) -- read A0,B0; stage A1,B1 of t+1 ----
        #pragma unroll
        for (int fm = 0; fm < 4; ++fm) {
            af[fm][0] = *(const bf16x8*)(LDS + aS0 + rowA + fm * 2048 + ck0);
            af[fm][1] = *(const bf16x8*)(LDS + aS0 + rowA + fm * 2048 + ck1);
        }
        #pragma unroll
        for (int fn = 0; fn < 2; ++fn) {
            b0[fn][0] = *(const bf16x8*)(LDS + bS0 + rowB + fn * 2048 + ck0);
            b0[fn][1] = *(const bf16x8*)(LDS + bS0 + rowB + fn * 2048 + ck1);
        }
        if (t + 1 < KT) { STG_A(t + 1, 1); STG_B(t + 1, 1); }
        BAR();
        __builtin_amdgcn_s_setprio(1);
        #pragma unroll
        for (int fm = 0; fm < 4; ++fm)
            #pragma unroll
            for (int fn = 0; fn < 2; ++fn) {
                acc[0][fm][0][fn] = __builtin_amdgcn_mfma_f32_16x16x32_bf16(af[fm][0], b0[fn][0], acc[0][fm][0][fn], 0, 0, 0);
                acc[0][fm][0][fn] = __builtin_amdgcn_mfma_f32_16x16x32_bf16(af[fm][1], b0[fn][1], acc[0][fm][0][fn], 0, 0, 0);
            }
        __builtin_amdgcn_s_setprio(0);
        BAR();

        // ---- phase 2: quadrant (0,1) -- read B1 ----
        #pragma unroll
        for (int fn = 0; fn < 2; ++fn) {
            b1[fn][0] = *(const bf16x8*)(LDS + bS1 + rowB + fn * 2048 + ck0);
            b1[fn][1] = *(const bf16x8*)(LDS + bS1 + rowB + fn * 2048 + ck1);
        }
        BAR();
        __builtin_amdgcn_s_setprio(1);
        #pragma unroll
        for (int fm = 0; fm < 4; ++fm)
            #pragma unroll
            for (int fn = 0; fn < 2; ++fn) {
                acc[0][fm][1][fn] = __builtin_amdgcn_mfma_f32_16x16x32_bf16(af[fm][0], b1[fn][0], acc[0][fm][1][fn], 0, 0, 0);
                acc[0][fm][1][fn] = __builtin_amdgcn_mfma_f32_16x16x32_bf16(af[fm][1], b1[fn][1], acc[0][fm][1][fn], 0, 0, 0);
            }
        __builtin_amdgcn_s_setprio(0);
        BAR();

        // ---- phase 3: quadrant (1,0) -- read A1; stage A0 of t+2 ----
        #pragma unroll
        for (int fm = 0; fm < 4; ++fm) {
            af[fm][0] = *(const bf16x8*)(LDS + aS1 + rowA + fm * 2048 + ck0);
            af[fm][1] = *(const bf16x8*)(LDS + aS1 + rowA + fm * 2048 + ck1);
        }
        if (t + 2 < KT) STG_A(t + 2, 0);
        BAR();
        __builtin_amdgcn_s_setprio(1);
        #pragma unroll
        for (int fm = 0; fm < 4; ++fm)
            #pragma unroll
            for (int fn = 0; fn < 2; ++fn) {
                acc[1][fm][0][fn] = __builtin_amdgcn_mfma_f32_16x16x32_bf16(af[fm][0], b0[fn][0], acc[1][fm][0][fn], 0, 0, 0);
                acc[1][fm][0][fn] = __builtin_amdgcn_mfma_f32_16x16x32_bf16(af[fm][1], b0[fn][1], acc[1][fm][0][fn], 0, 0, 0);
            }
        __builtin_amdgcn_s_setprio(0);
        BAR();

        // ---- phase 4: quadrant (1,1) -- stage B0 of t+2; counted vmcnt ----
        if (t + 2 < KT) STG_B(t + 2, 0);
        BAR();
        __builtin_amdgcn_s_setprio(1);
        #pragma unroll
        for (int fm = 0; fm < 4; ++fm)
            #pragma unroll
            for (int fn = 0; fn < 2; ++fn) {
                acc[1][fm][1][fn] = __builtin_amdgcn_mfma_f32_16x16x32_bf16(af[fm][0], b1[fn][0], acc[1][fm][1][fn], 0, 0, 0);
                acc[1][fm][1][fn] = __builtin_amdgcn_mfma_f32_16x16x32_bf16(af[fm][1], b1[fn][1], acc[1][fm][1][fn], 0, 0, 0);
            }
        __builtin_amdgcn_s_setprio(0);
        if (t + 2 < KT) asm volatile("s_waitcnt vmcnt(4)" ::: "memory");
        else            asm volatile("s_waitcnt vmcnt(0)" ::: "memory");
        BAR();
    }
#undef STG_A
#undef STG_B

    // ---- epilogue ----
    const int cr = (l >> 4) * 4;
    const int cl = l & 15;
    #pragma unroll
    for (int qn = 0; qn < 2; ++qn)
        #pragma unroll
        for (int fn = 0; fn < 2; ++fn) {
            const int col = tileN + qn * 128 + wn * 32 + fn * 16 + cl;
            const float bs = bias[col];
            float gt = 0.f;
            if (EPI == 0) gt = gate[col];
            #pragma unroll
            for (int qm = 0; qm < 2; ++qm)
                #pragma unroll
                for (int fm = 0; fm < 4; ++fm)
                    #pragma unroll
                    for (int r = 0; r < 4; ++r) {
                        const int row = tileM + qm * 128 + wm * 64 + fm * 16 + cr + r;
                        float v = acc[qm][fm][qn][fn][r] + bs;
                        if (EPI == 0) v = tanh_fast(v) * gt;
                        C[(size_t)row * N + col] = f2bf(v);
                    }
        }
}

// ---------------- row softmax + weighted sum + m_q_new ----------------
__global__ __launch_bounds__(256) void softmax_out(const u16* __restrict__ logits,
                                                   const float* __restrict__ hidden,
                                                   const float* __restrict__ m_q,
                                                   float* __restrict__ out,
                                                   int D, int R) {
    const int r = blockIdx.x;
    const int t = threadIdx.x;
    const int w = t >> 6, l = t & 63;
    const u16* lp = logits + (size_t)r * D + t * 8;
    const float* hp = hidden + (size_t)r * D + t * 8;

    bf16x8 lv = *(const bf16x8*)lp;
    float lf[8];
    #pragma unroll
    for (int j = 0; j < 8; ++j) lf[j] = bf2f((u16)lv[j]);
    float4 h0 = *(const float4*)hp;
    float4 h1 = *(const float4*)(hp + 4);
    float hv[8] = {h0.x, h0.y, h0.z, h0.w, h1.x, h1.y, h1.z, h1.w};

    float m = lf[0];
    #pragma unroll
    for (int j = 1; j < 8; ++j) m = fmaxf(m, lf[j]);
    #pragma unroll
    for (int o = 32; o >= 1; o >>= 1) m = fmaxf(m, __shfl_xor(m, o));

    __shared__ float red[8];
    if (l == 0) red[w] = m;
    __syncthreads();
    m = fmaxf(fmaxf(red[0], red[1]), fmaxf(red[2], red[3]));
    __syncthreads();

    float se = 0.f, sh = 0.f;
    #pragma unroll
    for (int j = 0; j < 8; ++j) {
        float e = __expf(lf[j] - m);
        se += e;
        sh += e * hv[j];
    }
    #pragma unroll
    for (int o = 32; o >= 1; o >>= 1) { se += __shfl_xor(se, o); sh += __shfl_xor(sh, o); }
    if (l == 0) { red[w] = se; red[4 + w] = sh; }
    __syncthreads();
    if (t == 0) {
        float SE = red[0] + red[1] + red[2] + red[3];
        float SH = red[4] + red[5] + red[6] + red[7];
        float o = SH / SE;
        out[r] = o;
        out[R + r] = m_q[r & (D - 1)] + o;
    }
}

extern "C" void kernel_launch(void* const* d_in, const int* in_sizes, int n_in,
                              void* d_out, int out_size, void* d_ws, size_t ws_size,
                              hipStream_t stream) {
    const float* hidden = (const float*)d_in[0];
    const float* m_q    = (const float*)d_in[1];
    const float* Wq     = (const float*)d_in[2];
    const float* bq     = (const float*)d_in[3];
    const float* Wm     = (const float*)d_in[4];
    const float* bm     = (const float*)d_in[5];
    const float* Wa     = (const float*)d_in[6];
    const float* ba     = (const float*)d_in[7];
    float* out = (float*)d_out;

    const int D = 2048;
    const int M = 16 * 2048;  // B*S = 32768

    char* ws = (char*)d_ws;
    size_t oH  = 0;
    size_t oS  = oH  + (size_t)M * D * 2;   // Sg bf16
    size_t oWq = oS  + (size_t)M * D * 2;
    size_t oWa = oWq + (size_t)D * D * 2;
    size_t oMq = oWa + (size_t)D * D * 2;
    size_t need = oMq + (size_t)D * sizeof(float);
    if (ws_size < need) return;

    u16* hbf    = (u16*)(ws + oH);
    u16* Sg     = (u16*)(ws + oS);
    u16* Wqb    = (u16*)(ws + oWq);
    u16* Wab    = (u16*)(ws + oWa);
    float* mq   = (float*)(ws + oMq);
    u16* logits = hbf;  // alias: hidden_bf16 dead after GEMM1

    cvt_f32_bf16<<<4096, 256, 0, stream>>>(hidden, hbf, M * D / 8);
    cvt_f32_bf16<<<1024, 256, 0, stream>>>(Wq, Wqb, D * D / 8);
    cvt_f32_bf16<<<1024, 256, 0, stream>>>(Wa, Wab, D * D / 8);
    mq_kernel<<<D / 4, 256, 0, stream>>>(Wm, m_q, bm, mq, D);

    dim3 grid(D / 256, M / 256);  // (8, 128)
    gemm8<0><<<grid, 512, 0, stream>>>(hbf, Wqb, bq, mq, Sg, M, D, D);
    gemm8<1><<<grid, 512, 0, stream>>>(Sg, Wab, ba, nullptr, logits, M, D, D);

    softmax_out<<<M, 256, 0, stream>>>(logits, hidden, m_q, out, D, M);
}

// Round 3
// 666.341 us; speedup vs baseline: 1.5023x; 1.0666x over previous
//
#include <hip/hip_runtime.h>

typedef unsigned short u16;
typedef short bf16x8 __attribute__((ext_vector_type(8)));
typedef u16 u16x8 __attribute__((ext_vector_type(8)));
typedef float f32x4 __attribute__((ext_vector_type(4)));

__device__ __forceinline__ float bf2f(u16 u) {
    union { unsigned u; float f; } c; c.u = ((unsigned)u) << 16; return c.f;
}
__device__ __forceinline__ u16 f2bf(float f) {
    union { float f; unsigned u; } c; c.f = f;
    unsigned r = c.u + 0x7FFFu + ((c.u >> 16) & 1u);
    return (u16)(r >> 16);
}
__device__ __forceinline__ float tanh_fast(float x) {
    float e = __expf(2.0f * x);
    return 1.0f - 2.0f / (e + 1.0f);
}
__device__ __forceinline__ void gll16(const void* g, void* l) {
    __builtin_amdgcn_global_load_lds((const __attribute__((address_space(1))) void*)g,
                                     (__attribute__((address_space(3))) void*)l, 16, 0, 0);
}

#define BAR() do { __builtin_amdgcn_sched_barrier(0); __builtin_amdgcn_s_barrier(); \
                   __builtin_amdgcn_sched_barrier(0); } while (0)

// ---------------- f32 -> bf16 convert, 8 elems/thread ----------------
__global__ __launch_bounds__(256) void cvt_f32_bf16(const float* __restrict__ src,
                                                    u16* __restrict__ dst, int n8) {
    int i = blockIdx.x * blockDim.x + threadIdx.x;
    int stride = gridDim.x * blockDim.x;
    for (; i < n8; i += stride) {
        const float4* s = (const float4*)(src + (size_t)i * 8);
        float4 a = s[0], b = s[1];
        u16x8 o;
        o[0] = f2bf(a.x); o[1] = f2bf(a.y); o[2] = f2bf(a.z); o[3] = f2bf(a.w);
        o[4] = f2bf(b.x); o[5] = f2bf(b.y); o[6] = f2bf(b.z); o[7] = f2bf(b.w);
        *(u16x8*)(dst + (size_t)i * 8) = o;
    }
}

// ---------------- mq = tanh(Wm @ m_q + bm), one wave per output ----------------
__global__ __launch_bounds__(256) void mq_kernel(const float* __restrict__ Wm,
                                                 const float* __restrict__ q,
                                                 const float* __restrict__ bm,
                                                 float* __restrict__ mq, int D) {
    int w = threadIdx.x >> 6, l = threadIdx.x & 63;
    int e = blockIdx.x * 4 + w;
    const float* wp = Wm + (size_t)e * D;
    float s = 0.f;
    for (int j = 0; j < D; j += 256) {
        float4 wv = *(const float4*)(wp + j + l * 4);
        float4 qv = *(const float4*)(q + j + l * 4);
        s += wv.x * qv.x + wv.y * qv.y + wv.z * qv.z + wv.w * qv.w;
    }
    #pragma unroll
    for (int o = 32; o >= 1; o >>= 1) s += __shfl_xor(s, o);
    if (l == 0) mq[e] = tanh_fast(s + bm[e]);
}

// ---------------- C[M,N] = A[M,K] @ B[N,K]^T : 256x256 8-phase template ----------------
// 8 waves (2M x 4N, interleaved quadrants), BK=64, 3-bit XOR LDS swizzle
// (physical 16B-slot = logical slot ^ (row&7)), counted vmcnt(4) per K-tile,
// setprio around MFMA clusters.
// EPI=0: C = bf16( tanh(acc+bias[col]) * gate[col] );  EPI=1: C = bf16(acc+bias[col])
template <int EPI>
__global__ __launch_bounds__(512, 2) void gemm8(const u16* __restrict__ A,
                                                const u16* __restrict__ B,
                                                const float* __restrict__ bias,
                                                const float* __restrict__ gate,
                                                u16* __restrict__ C,
                                                int M, int N, int K) {
    __shared__ u16 sh[65536];            // 128 KiB: A half-slots [4x16KB] | B half-slots [4x16KB]
    char* LDS = (char*)sh;
    const int K2 = K * 2;
    const int KT = K >> 6;               // K-tiles of 64

    const int tid = threadIdx.x;
    const int w = tid >> 6, l = tid & 63;
    const int wm = w >> 2, wn = w & 3;

    // XCD-aware swizzle (nwg = 1024, divisible by 8)
    int orig = blockIdx.x + gridDim.x * blockIdx.y;
    int nwg = gridDim.x * gridDim.y;
    int id = ((nwg & 7) == 0) ? ((orig & 7) * (nwg >> 3) + (orig >> 3)) : orig;
    const int tileN = (id % gridDim.x) * 256;
    const int tileM = (id / gridDim.x) * 256;

    // ---- staging geometry (pre-swizzled global source, linear LDS dest) ----
    // physical LDS byte = wj*1024 + l*16 -> row = wj*8 + (l>>3), phys slot = l&7.
    // logical slot = phys ^ (row&7) = (l&7) ^ (l>>3)  ->  global col byte:
    const int r0 = (w * 2) * 8 + (l >> 3);
    const int r1 = (w * 2 + 1) * 8 + (l >> 3);
    const int cc = ((l & 7) ^ (l >> 3)) << 4;     // 8-lane groups stay 128B-contiguous
    const char* srcA0 = (const char*)A + (size_t)(tileM + r0) * K2 + cc;
    const char* srcA1 = (const char*)A + (size_t)(tileM + r1) * K2 + cc;
    const char* srcB0 = (const char*)B + (size_t)(tileN + r0) * K2 + cc;
    const char* srcB1 = (const char*)B + (size_t)(tileN + r1) * K2 + cc;
    const int ldc0 = (w * 2) * 1024, ldc1 = (w * 2 + 1) * 1024;

#define STG_A(tk, h) do { size_t go = (size_t)(tk) * 128 + (size_t)(h) * 128 * K2; \
    int sb = ((((tk) & 1) * 2 + (h)) * 16384); \
    gll16(srcA0 + go, LDS + sb + ldc0); gll16(srcA1 + go, LDS + sb + ldc1); } while (0)
#define STG_B(tk, h) do { size_t go = (size_t)(tk) * 128 + (size_t)(h) * 128 * K2; \
    int sb = 65536 + ((((tk) & 1) * 2 + (h)) * 16384); \
    gll16(srcB0 + go, LDS + sb + ldc0); gll16(srcB1 + go, LDS + sb + ldc1); } while (0)

    // ---- reader geometry (swizzled ds_read: phys slot = logical slot ^ (row&7)) ----
    // fragment row = (l&15); row&7 = l&7. logical slot k-half0 = (l>>4), k-half1 = 4+(l>>4).
    const int sw = l & 7;
    const int rowA = (wm * 64 + (l & 15)) * 128;
    const int rowB = (wn * 32 + (l & 15)) * 128;
    const int ck0 = (((l >> 4) ^ sw) << 4);
    const int ck1 = (((4 + (l >> 4)) ^ sw) << 4);

    f32x4 acc[2][4][2][2] = {};

    // ---- prologue: tile0 all 4 halves + tile1 A0,B0 ----
    STG_A(0, 0); STG_A(0, 1); STG_B(0, 0); STG_B(0, 1);
    STG_A(1, 0); STG_B(1, 0);
    asm volatile("s_waitcnt vmcnt(4)" ::: "memory");   // tile0 landed, 2 halves in flight
    BAR();

    for (int t = 0; t < KT; ++t) {
        const int p = t & 1;
        const int aS0 = (p * 2) * 16384, aS1 = (p * 2 + 1) * 16384;
        const int bS0 = 65536 + (p * 2) * 16384, bS1 = 65536 + (p * 2 + 1) * 16384;
        bf16x8 af[4][2], b0[2][2], b1[2][2];

        // ---- phase 1: quadrant (0,0) -- read A0,B0; stage A1,B1 of t+1 ----
        #pragma unroll
        for (int fm = 0; fm < 4; ++fm) {
            af[fm][0] = *(const bf16x8*)(LDS + aS0 + rowA + fm * 2048 + ck0);
            af[fm][1] = *(const bf16x8*)(LDS + aS0 + rowA + fm * 2048 + ck1);
        }
        #pragma unroll
        for (int fn = 0; fn < 2; ++fn) {
            b0[fn][0] = *(const bf16x8*)(LDS + bS0 + rowB + fn * 2048 + ck0);
            b0[fn][1] = *(const bf16x8*)(LDS + bS0 + rowB + fn * 2048 + ck1);
        }
        if (t + 1 < KT) { STG_A(t + 1, 1); STG_B(t + 1, 1); }
        BAR();
        __builtin_amdgcn_s_setprio(1);
        #pragma unroll
        for (int fm = 0; fm < 4; ++fm)
            #pragma unroll
            for (int fn = 0; fn < 2; ++fn) {
                acc[0][fm][0][fn] = __builtin_amdgcn_mfma_f32_16x16x32_bf16(af[fm][0], b0[fn][0], acc[0][fm][0][fn], 0, 0, 0);
                acc[0][fm][0][fn] = __builtin_amdgcn_mfma_f32_16x16x32_bf16(af[fm][1], b0[fn][1], acc[0][fm][0][fn], 0, 0, 0);
            }
        __builtin_amdgcn_s_setprio(0);
        BAR();

        // ---- phase 2: quadrant (0,1) -- read B1 ----
        #pragma unroll
        for (int fn = 0; fn < 2; ++fn) {
            b1[fn][0] = *(const bf16x8*)(LDS + bS1 + rowB + fn * 2048 + ck0);
            b1[fn][1] = *(const bf16x8*)(LDS + bS1 + rowB + fn * 2048 + ck1);
        }
        BAR();
        __builtin_amdgcn_s_setprio(1);
        #pragma unroll
        for (int fm = 0; fm < 4; ++fm)
            #pragma unroll
            for (int fn = 0; fn < 2; ++fn) {
                acc[0][fm][1][fn] = __builtin_amdgcn_mfma_f32_16x16x32_bf16(af[fm][0], b1[fn][0], acc[0][fm][1][fn], 0, 0, 0);
                acc[0][fm][1][fn] = __builtin_amdgcn_mfma_f32_16x16x32_bf16(af[fm][1], b1[fn][1], acc[0][fm][1][fn], 0, 0, 0);
            }
        __builtin_amdgcn_s_setprio(0);
        BAR();

        // ---- phase 3: quadrant (1,0) -- read A1; stage A0 of t+2 ----
        #pragma unroll
        for (int fm = 0; fm < 4; ++fm) {
            af[fm][0] = *(const bf16x8*)(LDS + aS1 + rowA + fm * 2048 + ck0);
            af[fm][1] = *(const bf16x8*)(LDS + aS1 + rowA + fm * 2048 + ck1);
        }
        if (t + 2 < KT) STG_A(t + 2, 0);
        BAR();
        __builtin_amdgcn_s_setprio(1);
        #pragma unroll
        for (int fm = 0; fm < 4; ++fm)
            #pragma unroll
            for (int fn = 0; fn < 2; ++fn) {
                acc[1][fm][0][fn] = __builtin_amdgcn_mfma_f32_16x16x32_bf16(af[fm][0], b0[fn][0], acc[1][fm][0][fn], 0, 0, 0);
                acc[1][fm][0][fn] = __builtin_amdgcn_mfma_f32_16x16x32_bf16(af[fm][1], b0[fn][1], acc[1][fm][0][fn], 0, 0, 0);
            }
        __builtin_amdgcn_s_setprio(0);
        BAR();

        // ---- phase 4: quadrant (1,1) -- stage B0 of t+2; counted vmcnt ----
        if (t + 2 < KT) STG_B(t + 2, 0);
        BAR();
        __builtin_amdgcn_s_setprio(1);
        #pragma unroll
        for (int fm = 0; fm < 4; ++fm)
            #pragma unroll
            for (int fn = 0; fn < 2; ++fn) {
                acc[1][fm][1][fn] = __builtin_amdgcn_mfma_f32_16x16x32_bf16(af[fm][0], b1[fn][0], acc[1][fm][1][fn], 0, 0, 0);
                acc[1][fm][1][fn] = __builtin_amdgcn_mfma_f32_16x16x32_bf16(af[fm][1], b1[fn][1], acc[1][fm][1][fn], 0, 0, 0);
            }
        __builtin_amdgcn_s_setprio(0);
        if (t + 2 < KT) asm volatile("s_waitcnt vmcnt(4)" ::: "memory");
        else            asm volatile("s_waitcnt vmcnt(0)" ::: "memory");
        BAR();
    }
#undef STG_A
#undef STG_B

    // ---- epilogue ----
    const int cr = (l >> 4) * 4;
    const int cl = l & 15;
    #pragma unroll
    for (int qn = 0; qn < 2; ++qn)
        #pragma unroll
        for (int fn = 0; fn < 2; ++fn) {
            const int col = tileN + qn * 128 + wn * 32 + fn * 16 + cl;
            const float bs = bias[col];
            float gt = 0.f;
            if (EPI == 0) gt = gate[col];
            #pragma unroll
            for (int qm = 0; qm < 2; ++qm)
                #pragma unroll
                for (int fm = 0; fm < 4; ++fm)
                    #pragma unroll
                    for (int r = 0; r < 4; ++r) {
                        const int row = tileM + qm * 128 + wm * 64 + fm * 16 + cr + r;
                        float v = acc[qm][fm][qn][fn][r] + bs;
                        if (EPI == 0) v = tanh_fast(v) * gt;
                        C[(size_t)row * N + col] = f2bf(v);
                    }
        }
}

// ---------------- row softmax + weighted sum + m_q_new ----------------
__global__ __launch_bounds__(256) void softmax_out(const u16* __restrict__ logits,
                                                   const float* __restrict__ hidden,
                                                   const float* __restrict__ m_q,
                                                   float* __restrict__ out,
                                                   int D, int R) {
    const int r = blockIdx.x;
    const int t = threadIdx.x;
    const int w = t >> 6, l = t & 63;
    const u16* lp = logits + (size_t)r * D + t * 8;
    const float* hp = hidden + (size_t)r * D + t * 8;

    bf16x8 lv = *(const bf16x8*)lp;
    float lf[8];
    #pragma unroll
    for (int j = 0; j < 8; ++j) lf[j] = bf2f((u16)lv[j]);
    float4 h0 = *(const float4*)hp;
    float4 h1 = *(const float4*)(hp + 4);
    float hv[8] = {h0.x, h0.y, h0.z, h0.w, h1.x, h1.y, h1.z, h1.w};

    float m = lf[0];
    #pragma unroll
    for (int j = 1; j < 8; ++j) m = fmaxf(m, lf[j]);
    #pragma unroll
    for (int o = 32; o >= 1; o >>= 1) m = fmaxf(m, __shfl_xor(m, o));

    __shared__ float red[8];
    if (l == 0) red[w] = m;
    __syncthreads();
    m = fmaxf(fmaxf(red[0], red[1]), fmaxf(red[2], red[3]));
    __syncthreads();

    float se = 0.f, sh = 0.f;
    #pragma unroll
    for (int j = 0; j < 8; ++j) {
        float e = __expf(lf[j] - m);
        se += e;
        sh += e * hv[j];
    }
    #pragma unroll
    for (int o = 32; o >= 1; o >>= 1) { se += __shfl_xor(se, o); sh += __shfl_xor(sh, o); }
    if (l == 0) { red[w] = se; red[4 + w] = sh; }
    __syncthreads();
    if (t == 0) {
        float SE = red[0] + red[1] + red[2] + red[3];
        float SH = red[4] + red[5] + red[6] + red[7];
        float o = SH / SE;
        out[r] = o;
        out[R + r] = m_q[r & (D - 1)] + o;
    }
}

extern "C" void kernel_launch(void* const* d_in, const int* in_sizes, int n_in,
                              void* d_out, int out_size, void* d_ws, size_t ws_size,
                              hipStream_t stream) {
    const float* hidden = (const float*)d_in[0];
    const float* m_q    = (const float*)d_in[1];
    const float* Wq     = (const float*)d_in[2];
    const float* bq     = (const float*)d_in[3];
    const float* Wm     = (const float*)d_in[4];
    const float* bm     = (const float*)d_in[5];
    const float* Wa     = (const float*)d_in[6];
    const float* ba     = (const float*)d_in[7];
    float* out = (float*)d_out;

    const int D = 2048;
    const int M = 16 * 2048;  // B*S = 32768

    char* ws = (char*)d_ws;
    size_t oH  = 0;
    size_t oS  = oH  + (size_t)M * D * 2;   // Sg bf16
    size_t oWq = oS  + (size_t)M * D * 2;
    size_t oWa = oWq + (size_t)D * D * 2;
    size_t oMq = oWa + (size_t)D * D * 2;
    size_t need = oMq + (size_t)D * sizeof(float);
    if (ws_size < need) return;

    u16* hbf    = (u16*)(ws + oH);
    u16* Sg     = (u16*)(ws + oS);
    u16* Wqb    = (u16*)(ws + oWq);
    u16* Wab    = (u16*)(ws + oWa);
    float* mq   = (float*)(ws + oMq);
    u16* logits = hbf;  // alias: hidden_bf16 dead after GEMM1

    cvt_f32_bf16<<<4096, 256, 0, stream>>>(hidden, hbf, M * D / 8);
    cvt_f32_bf16<<<1024, 256, 0, stream>>>(Wq, Wqb, D * D / 8);
    cvt_f32_bf16<<<1024, 256, 0, stream>>>(Wa, Wab, D * D / 8);
    mq_kernel<<<D / 4, 256, 0, stream>>>(Wm, m_q, bm, mq, D);

    dim3 grid(D / 256, M / 256);  // (8, 128)
    gemm8<0><<<grid, 512, 0, stream>>>(hbf, Wqb, bq, mq, Sg, M, D, D);
    gemm8<1><<<grid, 512, 0, stream>>>(Sg, Wab, ba, nullptr, logits, M, D, D);

    softmax_out<<<M, 256, 0, stream>>>(logits, hidden, m_q, out, D, M);
}

// Round 4
// 659.710 us; speedup vs baseline: 1.5174x; 1.0101x over previous
//
#include <hip/hip_runtime.h>

typedef unsigned short u16;
typedef short bf16x8 __attribute__((ext_vector_type(8)));
typedef u16 u16x8 __attribute__((ext_vector_type(8)));
typedef float f32x4 __attribute__((ext_vector_type(4)));

__device__ __forceinline__ float bf2f(u16 u) {
    union { unsigned u; float f; } c; c.u = ((unsigned)u) << 16; return c.f;
}
__device__ __forceinline__ u16 f2bf(float f) {
    union { float f; unsigned u; } c; c.f = f;
    unsigned r = c.u + 0x7FFFu + ((c.u >> 16) & 1u);
    return (u16)(r >> 16);
}
__device__ __forceinline__ float tanh_fast(float x) {
    float e = __expf(2.0f * x);
    return 1.0f - 2.0f / (e + 1.0f);
}
__device__ __forceinline__ void gll16(const void* g, void* l) {
    __builtin_amdgcn_global_load_lds((const __attribute__((address_space(1))) void*)g,
                                     (__attribute__((address_space(3))) void*)l, 16, 0, 0);
}

#define BAR() do { __builtin_amdgcn_sched_barrier(0); __builtin_amdgcn_s_barrier(); \
                   __builtin_amdgcn_sched_barrier(0); } while (0)

// ---------------- f32 -> bf16 convert, 8 elems/thread ----------------
__global__ __launch_bounds__(256) void cvt_f32_bf16(const float* __restrict__ src,
                                                    u16* __restrict__ dst, int n8) {
    int i = blockIdx.x * blockDim.x + threadIdx.x;
    int stride = gridDim.x * blockDim.x;
    for (; i < n8; i += stride) {
        const float4* s = (const float4*)(src + (size_t)i * 8);
        float4 a = s[0], b = s[1];
        u16x8 o;
        o[0] = f2bf(a.x); o[1] = f2bf(a.y); o[2] = f2bf(a.z); o[3] = f2bf(a.w);
        o[4] = f2bf(b.x); o[5] = f2bf(b.y); o[6] = f2bf(b.z); o[7] = f2bf(b.w);
        *(u16x8*)(dst + (size_t)i * 8) = o;
    }
}

// ---------------- mq = tanh(Wm @ m_q + bm), one wave per output ----------------
__global__ __launch_bounds__(256) void mq_kernel(const float* __restrict__ Wm,
                                                 const float* __restrict__ q,
                                                 const float* __restrict__ bm,
                                                 float* __restrict__ mq, int D) {
    int w = threadIdx.x >> 6, l = threadIdx.x & 63;
    int e = blockIdx.x * 4 + w;
    const float* wp = Wm + (size_t)e * D;
    float s = 0.f;
    for (int j = 0; j < D; j += 256) {
        float4 wv = *(const float4*)(wp + j + l * 4);
        float4 qv = *(const float4*)(q + j + l * 4);
        s += wv.x * qv.x + wv.y * qv.y + wv.z * qv.z + wv.w * qv.w;
    }
    #pragma unroll
    for (int o = 32; o >= 1; o >>= 1) s += __shfl_xor(s, o);
    if (l == 0) mq[e] = tanh_fast(s + bm[e]);
}

// ---------------- C[M,N] = A[M,K] @ B[N,K]^T : 256x256 8-phase template ----------------
// 8 waves (2M x 4N), BK=64, 3-bit XOR LDS swizzle, K-loop unrolled x2 so all
// ds_read addresses are base-VGPR + literal offset:, staging spread 2-2-2-2,
// counted vmcnt(4) per K-tile, setprio around MFMA clusters.
// EPI=0: C = bf16( tanh(acc+bias[col]) * gate[col] );  EPI=1: C = bf16(acc+bias[col])
template <int EPI>
__global__ __launch_bounds__(512, 2) void gemm8(const u16* __restrict__ A,
                                                const u16* __restrict__ B,
                                                const float* __restrict__ bias,
                                                const float* __restrict__ gate,
                                                u16* __restrict__ C,
                                                int M, int N, int K) {
    __shared__ u16 sh[65536];            // 128 KiB: A slots 0..3 @0, B slots 0..3 @65536
    char* LDS = (char*)sh;
    const int K2 = K * 2;
    const int KT = K >> 6;               // K-tiles of 64 (must be even)

    const int tid = threadIdx.x;
    const int w = tid >> 6, l = tid & 63;
    const int wm = w >> 2, wn = w & 3;

    // XCD-aware swizzle (nwg = 1024, divisible by 8)
    int orig = blockIdx.x + gridDim.x * blockIdx.y;
    int nwg = gridDim.x * gridDim.y;
    int id = ((nwg & 7) == 0) ? ((orig & 7) * (nwg >> 3) + (orig >> 3)) : orig;
    const int tileN = (id % gridDim.x) * 256;
    const int tileM = (id / gridDim.x) * 256;

    // ---- staging geometry (pre-swizzled global source, linear LDS dest) ----
    // physical LDS byte = wj*1024 + l*16 -> row = wj*8 + (l>>3), phys slot = l&7.
    // logical slot = phys ^ (row&7) = (l&7) ^ (l>>3)  ->  global col byte:
    const int r0 = (w * 2) * 8 + (l >> 3);
    const int r1 = (w * 2 + 1) * 8 + (l >> 3);
    const int cc = ((l & 7) ^ (l >> 3)) << 4;
    const char* srcA0 = (const char*)A + (size_t)(tileM + r0) * K2 + cc;
    const char* srcA1 = (const char*)A + (size_t)(tileM + r1) * K2 + cc;
    const char* srcB0 = (const char*)B + (size_t)(tileN + r0) * K2 + cc;
    const char* srcB1 = (const char*)B + (size_t)(tileN + r1) * K2 + cc;
    const int ldc0 = (w * 2) * 1024, ldc1 = (w * 2 + 1) * 1024;

#define STG_A(tk, h) do { size_t go = (size_t)(tk) * 128 + (size_t)(h) * 128 * K2; \
    int sb = ((((tk) & 1) * 2 + (h)) * 16384); \
    gll16(srcA0 + go, LDS + sb + ldc0); gll16(srcA1 + go, LDS + sb + ldc1); } while (0)
#define STG_B(tk, h) do { size_t go = (size_t)(tk) * 128 + (size_t)(h) * 128 * K2; \
    int sb = 65536 + ((((tk) & 1) * 2 + (h)) * 16384); \
    gll16(srcB0 + go, LDS + sb + ldc0); gll16(srcB1 + go, LDS + sb + ldc1); } while (0)

    // ---- reader bases: 4 VGPRs, all reads become base + literal offset ----
    const int sw = l & 7;
    const int rowA = (wm * 64 + (l & 15)) * 128;
    const int rowB = (wn * 32 + (l & 15)) * 128;
    const int ck0 = (((l >> 4) ^ sw) << 4);
    const int ck1 = (((4 + (l >> 4)) ^ sw) << 4);
    const char* pA0 = LDS + rowA + ck0;
    const char* pA1 = LDS + rowA + ck1;
    const char* pB0 = LDS + 65536 + rowB + ck0;   // B region bias folded into base
    const char* pB1 = LDS + 65536 + rowB + ck1;

    f32x4 acc[2][4][2][2] = {};

    // ---- prologue: tile0 all 4 halves + tile1 A0,B0 (12 loads, wait to 4) ----
    STG_A(0, 0); STG_A(0, 1); STG_B(0, 0); STG_B(0, 1);
    STG_A(1, 0); STG_B(1, 0);
    asm volatile("s_waitcnt vmcnt(4)" ::: "memory");
    BAR();

#define MFMA_CLUSTER(QM, QN, AF, BF)                                            \
    __builtin_amdgcn_s_setprio(1);                                              \
    _Pragma("unroll")                                                           \
    for (int fm = 0; fm < 4; ++fm)                                              \
        _Pragma("unroll")                                                       \
        for (int fn = 0; fn < 2; ++fn) {                                        \
            acc[QM][fm][QN][fn] = __builtin_amdgcn_mfma_f32_16x16x32_bf16(      \
                AF[fm][0], BF[fn][0], acc[QM][fm][QN][fn], 0, 0, 0);            \
            acc[QM][fm][QN][fn] = __builtin_amdgcn_mfma_f32_16x16x32_bf16(      \
                AF[fm][1], BF[fn][1], acc[QM][fm][QN][fn], 0, 0, 0);            \
        }                                                                       \
    __builtin_amdgcn_s_setprio(0);

#define ITER(t, P) do {                                                         \
    constexpr int A0O = (2 * (P)) * 16384;                                      \
    constexpr int A1O = (2 * (P) + 1) * 16384;                                  \
    bf16x8 af[4][2], b0[2][2], b1[2][2];                                        \
    /* phase 1: read A0+B0 (12), stage A1(t+1) */                               \
    _Pragma("unroll")                                                           \
    for (int fm = 0; fm < 4; ++fm) {                                            \
        af[fm][0] = *(const bf16x8*)(pA0 + A0O + fm * 2048);                    \
        af[fm][1] = *(const bf16x8*)(pA1 + A0O + fm * 2048);                    \
    }                                                                           \
    _Pragma("unroll")                                                           \
    for (int fn = 0; fn < 2; ++fn) {                                            \
        b0[fn][0] = *(const bf16x8*)(pB0 + A0O + fn * 2048);                    \
        b0[fn][1] = *(const bf16x8*)(pB1 + A0O + fn * 2048);                    \
    }                                                                           \
    if ((t) + 1 < KT) STG_A((t) + 1, 1);                                        \
    BAR();                                                                      \
    MFMA_CLUSTER(0, 0, af, b0)                                                  \
    BAR();                                                                      \
    /* phase 2: read B1 (4), stage B1(t+1) */                                   \
    _Pragma("unroll")                                                           \
    for (int fn = 0; fn < 2; ++fn) {                                            \
        b1[fn][0] = *(const bf16x8*)(pB0 + A1O + fn * 2048);                    \
        b1[fn][1] = *(const bf16x8*)(pB1 + A1O + fn * 2048);                    \
    }                                                                           \
    if ((t) + 1 < KT) STG_B((t) + 1, 1);                                        \
    BAR();                                                                      \
    MFMA_CLUSTER(0, 1, af, b1)                                                  \
    BAR();                                                                      \
    /* phase 3: read A1 (8), stage A0(t+2) */                                   \
    _Pragma("unroll")                                                           \
    for (int fm = 0; fm < 4; ++fm) {                                            \
        af[fm][0] = *(const bf16x8*)(pA0 + A1O + fm * 2048);                    \
        af[fm][1] = *(const bf16x8*)(pA1 + A1O + fm * 2048);                    \
    }                                                                           \
    if ((t) + 2 < KT) STG_A((t) + 2, 0);                                        \
    BAR();                                                                      \
    MFMA_CLUSTER(1, 0, af, b0)                                                  \
    BAR();                                                                      \
    /* phase 4: stage B0(t+2), counted vmcnt */                                 \
    if ((t) + 2 < KT) STG_B((t) + 2, 0);                                        \
    BAR();                                                                      \
    MFMA_CLUSTER(1, 1, af, b1)                                                  \
    if ((t) + 2 < KT) asm volatile("s_waitcnt vmcnt(4)" ::: "memory");          \
    else              asm volatile("s_waitcnt vmcnt(0)" ::: "memory");          \
    BAR();                                                                      \
} while (0)

    for (int tt = 0; tt < KT; tt += 2) {
        ITER(tt, 0);
        ITER(tt + 1, 1);
    }
#undef ITER
#undef MFMA_CLUSTER
#undef STG_A
#undef STG_B

    // ---- epilogue: C/D layout col = lane&15, row = (lane>>4)*4 + reg ----
    const int cr = (l >> 4) * 4;
    const int cl = l & 15;
    #pragma unroll
    for (int qn = 0; qn < 2; ++qn)
        #pragma unroll
        for (int fn = 0; fn < 2; ++fn) {
            const int col = tileN + qn * 128 + wn * 32 + fn * 16 + cl;
            const float bs = bias[col];
            float gt = 0.f;
            if (EPI == 0) gt = gate[col];
            #pragma unroll
            for (int qm = 0; qm < 2; ++qm)
                #pragma unroll
                for (int fm = 0; fm < 4; ++fm)
                    #pragma unroll
                    for (int r = 0; r < 4; ++r) {
                        const int row = tileM + qm * 128 + wm * 64 + fm * 16 + cr + r;
                        float v = acc[qm][fm][qn][fn][r] + bs;
                        if (EPI == 0) v = tanh_fast(v) * gt;
                        C[(size_t)row * N + col] = f2bf(v);
                    }
        }
}

// ---------------- row softmax + weighted sum + m_q_new ----------------
__global__ __launch_bounds__(256) void softmax_out(const u16* __restrict__ logits,
                                                   const float* __restrict__ hidden,
                                                   const float* __restrict__ m_q,
                                                   float* __restrict__ out,
                                                   int D, int R) {
    const int r = blockIdx.x;
    const int t = threadIdx.x;
    const int w = t >> 6, l = t & 63;
    const u16* lp = logits + (size_t)r * D + t * 8;
    const float* hp = hidden + (size_t)r * D + t * 8;

    bf16x8 lv = *(const bf16x8*)lp;
    float lf[8];
    #pragma unroll
    for (int j = 0; j < 8; ++j) lf[j] = bf2f((u16)lv[j]);
    float4 h0 = *(const float4*)hp;
    float4 h1 = *(const float4*)(hp + 4);
    float hv[8] = {h0.x, h0.y, h0.z, h0.w, h1.x, h1.y, h1.z, h1.w};

    float m = lf[0];
    #pragma unroll
    for (int j = 1; j < 8; ++j) m = fmaxf(m, lf[j]);
    #pragma unroll
    for (int o = 32; o >= 1; o >>= 1) m = fmaxf(m, __shfl_xor(m, o));

    __shared__ float red[8];
    if (l == 0) red[w] = m;
    __syncthreads();
    m = fmaxf(fmaxf(red[0], red[1]), fmaxf(red[2], red[3]));
    __syncthreads();

    float se = 0.f, sh = 0.f;
    #pragma unroll
    for (int j = 0; j < 8; ++j) {
        float e = __expf(lf[j] - m);
        se += e;
        sh += e * hv[j];
    }
    #pragma unroll
    for (int o = 32; o >= 1; o >>= 1) { se += __shfl_xor(se, o); sh += __shfl_xor(sh, o); }
    if (l == 0) { red[w] = se; red[4 + w] = sh; }
    __syncthreads();
    if (t == 0) {
        float SE = red[0] + red[1] + red[2] + red[3];
        float SH = red[4] + red[5] + red[6] + red[7];
        float o = SH / SE;
        out[r] = o;
        out[R + r] = m_q[r & (D - 1)] + o;
    }
}

extern "C" void kernel_launch(void* const* d_in, const int* in_sizes, int n_in,
                              void* d_out, int out_size, void* d_ws, size_t ws_size,
                              hipStream_t stream) {
    const float* hidden = (const float*)d_in[0];
    const float* m_q    = (const float*)d_in[1];
    const float* Wq     = (const float*)d_in[2];
    const float* bq     = (const float*)d_in[3];
    const float* Wm     = (const float*)d_in[4];
    const float* bm     = (const float*)d_in[5];
    const float* Wa     = (const float*)d_in[6];
    const float* ba     = (const float*)d_in[7];
    float* out = (float*)d_out;

    const int D = 2048;
    const int M = 16 * 2048;  // B*S = 32768

    char* ws = (char*)d_ws;
    size_t oH  = 0;
    size_t oS  = oH  + (size_t)M * D * 2;   // Sg bf16
    size_t oWq = oS  + (size_t)M * D * 2;
    size_t oWa = oWq + (size_t)D * D * 2;
    size_t oMq = oWa + (size_t)D * D * 2;
    size_t need = oMq + (size_t)D * sizeof(float);
    if (ws_size < need) return;

    u16* hbf    = (u16*)(ws + oH);
    u16* Sg     = (u16*)(ws + oS);
    u16* Wqb    = (u16*)(ws + oWq);
    u16* Wab    = (u16*)(ws + oWa);
    float* mq   = (float*)(ws + oMq);
    u16* logits = hbf;  // alias: hidden_bf16 dead after GEMM1

    cvt_f32_bf16<<<4096, 256, 0, stream>>>(hidden, hbf, M * D / 8);
    cvt_f32_bf16<<<1024, 256, 0, stream>>>(Wq, Wqb, D * D / 8);
    cvt_f32_bf16<<<1024, 256, 0, stream>>>(Wa, Wab, D * D / 8);
    mq_kernel<<<D / 4, 256, 0, stream>>>(Wm, m_q, bm, mq, D);

    dim3 grid(D / 256, M / 256);  // (8, 128)
    gemm8<0><<<grid, 512, 0, stream>>>(hbf, Wqb, bq, mq, Sg, M, D, D);
    gemm8<1><<<grid, 512, 0, stream>>>(Sg, Wab, ba, nullptr, logits, M, D, D);

    softmax_out<<<M, 256, 0, stream>>>(logits, hidden, m_q, out, D, M);
}

// Round 5
// 655.457 us; speedup vs baseline: 1.5273x; 1.0065x over previous
//
#include <hip/hip_runtime.h>

typedef unsigned short u16;
typedef short bf16x8 __attribute__((ext_vector_type(8)));
typedef u16 u16x8 __attribute__((ext_vector_type(8)));
typedef float f32x4 __attribute__((ext_vector_type(4)));

__device__ __forceinline__ float bf2f(u16 u) {
    union { unsigned u; float f; } c; c.u = ((unsigned)u) << 16; return c.f;
}
__device__ __forceinline__ u16 f2bf(float f) {
    union { float f; unsigned u; } c; c.f = f;
    unsigned r = c.u + 0x7FFFu + ((c.u >> 16) & 1u);
    return (u16)(r >> 16);
}
__device__ __forceinline__ float tanh_fast(float x) {
    float e = __expf(2.0f * x);
    return 1.0f - 2.0f / (e + 1.0f);
}
__device__ __forceinline__ void gll16(const void* g, void* l) {
    __builtin_amdgcn_global_load_lds((const __attribute__((address_space(1))) void*)g,
                                     (__attribute__((address_space(3))) void*)l, 16, 0, 0);
}

#define BAR() do { __builtin_amdgcn_sched_barrier(0); __builtin_amdgcn_s_barrier(); \
                   __builtin_amdgcn_sched_barrier(0); } while (0)

// ---------------- f32 -> bf16 convert, 8 elems/thread ----------------
__global__ __launch_bounds__(256) void cvt_f32_bf16(const float* __restrict__ src,
                                                    u16* __restrict__ dst, int n8) {
    int i = blockIdx.x * blockDim.x + threadIdx.x;
    int stride = gridDim.x * blockDim.x;
    for (; i < n8; i += stride) {
        const float4* s = (const float4*)(src + (size_t)i * 8);
        float4 a = s[0], b = s[1];
        u16x8 o;
        o[0] = f2bf(a.x); o[1] = f2bf(a.y); o[2] = f2bf(a.z); o[3] = f2bf(a.w);
        o[4] = f2bf(b.x); o[5] = f2bf(b.y); o[6] = f2bf(b.z); o[7] = f2bf(b.w);
        *(u16x8*)(dst + (size_t)i * 8) = o;
    }
}

// ---------------- mq = tanh(Wm @ m_q + bm), one wave per output ----------------
__global__ __launch_bounds__(256) void mq_kernel(const float* __restrict__ Wm,
                                                 const float* __restrict__ q,
                                                 const float* __restrict__ bm,
                                                 float* __restrict__ mq, int D) {
    int w = threadIdx.x >> 6, l = threadIdx.x & 63;
    int e = blockIdx.x * 4 + w;
    const float* wp = Wm + (size_t)e * D;
    float s = 0.f;
    for (int j = 0; j < D; j += 256) {
        float4 wv = *(const float4*)(wp + j + l * 4);
        float4 qv = *(const float4*)(q + j + l * 4);
        s += wv.x * qv.x + wv.y * qv.y + wv.z * qv.z + wv.w * qv.w;
    }
    #pragma unroll
    for (int o = 32; o >= 1; o >>= 1) s += __shfl_xor(s, o);
    if (l == 0) mq[e] = tanh_fast(s + bm[e]);
}

// ---------------- C[M,N] = A[M,K] @ B[N,K]^T : 256x256, reads pipelined 1 phase ahead ----
// 8 waves (2M x 4N), BK=64, 3-bit XOR LDS swizzle, 4 phases/K-tile, 1 barrier/phase.
// Each phase: MFMA cluster (operands loaded LAST phase) || next phase's ds_reads || 1 STG.
// vmcnt ledger (per-wave vmcnt + barrier seals a slot):
//   prologue vmcnt(4) covers all tile0 slots; W3=vmcnt(6) seals A0/B0(t+1) for ph4 reads;
//   W4=vmcnt(4) seals A1/B1(t+1) for ph1/ph2 of t+1. Steady-state in-flight 4-10 loads.
// EPI=0: C = bf16( tanh(acc+bias[col]) * gate[col] );  EPI=1: C = bf16(acc+bias[col])
template <int EPI>
__global__ __launch_bounds__(512, 2) void gemm8(const u16* __restrict__ A,
                                                const u16* __restrict__ B,
                                                const float* __restrict__ bias,
                                                const float* __restrict__ gate,
                                                u16* __restrict__ C,
                                                int M, int N, int K) {
    __shared__ u16 sh[65536];            // 128 KiB: A slots 0..3 @0, B slots 0..3 @65536
    char* LDS = (char*)sh;
    const int K2 = K * 2;
    const int KT = K >> 6;               // K-tiles of 64 (must be even)

    const int tid = threadIdx.x;
    const int w = tid >> 6, l = tid & 63;
    const int wm = w >> 2, wn = w & 3;

    // XCD-aware swizzle (nwg = 1024, divisible by 8)
    int orig = blockIdx.x + gridDim.x * blockIdx.y;
    int nwg = gridDim.x * gridDim.y;
    int id = ((nwg & 7) == 0) ? ((orig & 7) * (nwg >> 3) + (orig >> 3)) : orig;
    const int tileN = (id % gridDim.x) * 256;
    const int tileM = (id / gridDim.x) * 256;

    // ---- staging geometry (pre-swizzled global source, linear LDS dest) ----
    const int r0 = (w * 2) * 8 + (l >> 3);
    const int r1 = (w * 2 + 1) * 8 + (l >> 3);
    const int cc = ((l & 7) ^ (l >> 3)) << 4;
    const char* srcA0 = (const char*)A + (size_t)(tileM + r0) * K2 + cc;
    const char* srcA1 = (const char*)A + (size_t)(tileM + r1) * K2 + cc;
    const char* srcB0 = (const char*)B + (size_t)(tileN + r0) * K2 + cc;
    const char* srcB1 = (const char*)B + (size_t)(tileN + r1) * K2 + cc;
    const int ldc0 = (w * 2) * 1024, ldc1 = (w * 2 + 1) * 1024;

#define STG_A(tk, h) do { size_t go = (size_t)(tk) * 128 + (size_t)(h) * 128 * K2; \
    int sb = ((((tk) & 1) * 2 + (h)) * 16384); \
    gll16(srcA0 + go, LDS + sb + ldc0); gll16(srcA1 + go, LDS + sb + ldc1); } while (0)
#define STG_B(tk, h) do { size_t go = (size_t)(tk) * 128 + (size_t)(h) * 128 * K2; \
    int sb = 65536 + ((((tk) & 1) * 2 + (h)) * 16384); \
    gll16(srcB0 + go, LDS + sb + ldc0); gll16(srcB1 + go, LDS + sb + ldc1); } while (0)

    // ---- reader bases: base VGPR + literal offset ----
    const int sw = l & 7;
    const int rowA = (wm * 64 + (l & 15)) * 128;
    const int rowB = (wn * 32 + (l & 15)) * 128;
    const int ck0 = (((l >> 4) ^ sw) << 4);
    const int ck1 = (((4 + (l >> 4)) ^ sw) << 4);
    const char* pA0 = LDS + rowA + ck0;
    const char* pA1 = LDS + rowA + ck1;
    const char* pB0 = LDS + 65536 + rowB + ck0;
    const char* pB1 = LDS + 65536 + rowB + ck1;

    f32x4 acc[2][4][2][2] = {};
    bf16x8 afA[4][2], afB[4][2], bb0[2][2], bb1[2][2];

    // ---- prologue: tile0 (all 4 halves) + tile1 A0,B0; seal tile0; pre-read afA,bb0 ----
    STG_A(0, 0); STG_B(0, 0); STG_A(0, 1); STG_B(0, 1);
    STG_A(1, 0); STG_B(1, 0);
    asm volatile("s_waitcnt vmcnt(4)" ::: "memory");   // tile0 fully landed; tile1 A0,B0 in flight
    BAR();
    #pragma unroll
    for (int fm = 0; fm < 4; ++fm) {
        afA[fm][0] = *(const bf16x8*)(pA0 + fm * 2048);
        afA[fm][1] = *(const bf16x8*)(pA1 + fm * 2048);
    }
    #pragma unroll
    for (int fn = 0; fn < 2; ++fn) {
        bb0[fn][0] = *(const bf16x8*)(pB0 + fn * 2048);
        bb0[fn][1] = *(const bf16x8*)(pB1 + fn * 2048);
    }

#define MFMA_CLUSTER(QM, QN, AF, BF)                                            \
    __builtin_amdgcn_s_setprio(1);                                              \
    _Pragma("unroll")                                                           \
    for (int fm = 0; fm < 4; ++fm)                                              \
        _Pragma("unroll")                                                       \
        for (int fn = 0; fn < 2; ++fn) {                                        \
            acc[QM][fm][QN][fn] = __builtin_amdgcn_mfma_f32_16x16x32_bf16(      \
                AF[fm][0], BF[fn][0], acc[QM][fm][QN][fn], 0, 0, 0);            \
            acc[QM][fm][QN][fn] = __builtin_amdgcn_mfma_f32_16x16x32_bf16(      \
                AF[fm][1], BF[fn][1], acc[QM][fm][QN][fn], 0, 0, 0);            \
        }                                                                       \
    __builtin_amdgcn_s_setprio(0);

#define ITER(t, P) do {                                                         \
    constexpr int S1 = (2 * (P) + 1) * 16384;                                   \
    constexpr int SN = (2 * (1 - (P))) * 16384;                                 \
    /* ph1: MFMA Q00(afA,bb0) || read bb1 <- B1(t) || stage A1(t+1) */          \
    if ((t) + 1 < KT) STG_A((t) + 1, 1);                                        \
    _Pragma("unroll")                                                           \
    for (int fn = 0; fn < 2; ++fn) {                                            \
        bb1[fn][0] = *(const bf16x8*)(pB0 + S1 + fn * 2048);                    \
        bb1[fn][1] = *(const bf16x8*)(pB1 + S1 + fn * 2048);                    \
    }                                                                           \
    MFMA_CLUSTER(0, 0, afA, bb0)                                                \
    BAR();                                                                      \
    /* ph2: MFMA Q01(afA,bb1) || read afB <- A1(t) || stage B1(t+1) */          \
    if ((t) + 1 < KT) STG_B((t) + 1, 1);                                        \
    _Pragma("unroll")                                                           \
    for (int fm = 0; fm < 4; ++fm) {                                            \
        afB[fm][0] = *(const bf16x8*)(pA0 + S1 + fm * 2048);                    \
        afB[fm][1] = *(const bf16x8*)(pA1 + S1 + fm * 2048);                    \
    }                                                                           \
    MFMA_CLUSTER(0, 1, afA, bb1)                                                \
    BAR();                                                                      \
    /* ph3: MFMA Q10(afB,bb0) || stage A0(t+2); W3 seals A0/B0(t+1) */          \
    if ((t) + 2 < KT) { STG_A((t) + 2, 0);                                      \
        asm volatile("s_waitcnt vmcnt(6)" ::: "memory"); }                      \
    else if ((t) + 1 < KT)                                                      \
        asm volatile("s_waitcnt vmcnt(4)" ::: "memory");                        \
    MFMA_CLUSTER(1, 0, afB, bb0)                                                \
    BAR();                                                                      \
    /* ph4: MFMA Q11(afB,bb1) || stage B0(t+2); W4 seals A1/B1(t+1);            \
       read-ahead afA,bb0 <- A0,B0(t+1) */                                      \
    if ((t) + 2 < KT) { STG_B((t) + 2, 0);                                      \
        asm volatile("s_waitcnt vmcnt(4)" ::: "memory"); }                      \
    else if ((t) + 1 < KT)                                                      \
        asm volatile("s_waitcnt vmcnt(0)" ::: "memory");                        \
    if ((t) + 1 < KT) {                                                         \
        _Pragma("unroll")                                                       \
        for (int fm = 0; fm < 4; ++fm) {                                        \
            afA[fm][0] = *(const bf16x8*)(pA0 + SN + fm * 2048);                \
            afA[fm][1] = *(const bf16x8*)(pA1 + SN + fm * 2048);                \
        }                                                                       \
        _Pragma("unroll")                                                       \
        for (int fn = 0; fn < 2; ++fn) {                                        \
            bb0[fn][0] = *(const bf16x8*)(pB0 + SN + fn * 2048);                \
            bb0[fn][1] = *(const bf16x8*)(pB1 + SN + fn * 2048);                \
        }                                                                       \
    }                                                                           \
    MFMA_CLUSTER(1, 1, afB, bb1)                                                \
    BAR();                                                                      \
} while (0)

    for (int tt = 0; tt < KT; tt += 2) {
        ITER(tt, 0);
        ITER(tt + 1, 1);
    }
#undef ITER
#undef MFMA_CLUSTER
#undef STG_A
#undef STG_B

    // ---- epilogue: C/D layout col = lane&15, row = (lane>>4)*4 + reg ----
    const int cr = (l >> 4) * 4;
    const int cl = l & 15;
    #pragma unroll
    for (int qn = 0; qn < 2; ++qn)
        #pragma unroll
        for (int fn = 0; fn < 2; ++fn) {
            const int col = tileN + qn * 128 + wn * 32 + fn * 16 + cl;
            const float bs = bias[col];
            float gt = 0.f;
            if (EPI == 0) gt = gate[col];
            #pragma unroll
            for (int qm = 0; qm < 2; ++qm)
                #pragma unroll
                for (int fm = 0; fm < 4; ++fm)
                    #pragma unroll
                    for (int r = 0; r < 4; ++r) {
                        const int row = tileM + qm * 128 + wm * 64 + fm * 16 + cr + r;
                        float v = acc[qm][fm][qn][fn][r] + bs;
                        if (EPI == 0) v = tanh_fast(v) * gt;
                        C[(size_t)row * N + col] = f2bf(v);
                    }
        }
}

// ---------------- row softmax + weighted sum + m_q_new ----------------
__global__ __launch_bounds__(256) void softmax_out(const u16* __restrict__ logits,
                                                   const float* __restrict__ hidden,
                                                   const float* __restrict__ m_q,
                                                   float* __restrict__ out,
                                                   int D, int R) {
    const int r = blockIdx.x;
    const int t = threadIdx.x;
    const int w = t >> 6, l = t & 63;
    const u16* lp = logits + (size_t)r * D + t * 8;
    const float* hp = hidden + (size_t)r * D + t * 8;

    bf16x8 lv = *(const bf16x8*)lp;
    float lf[8];
    #pragma unroll
    for (int j = 0; j < 8; ++j) lf[j] = bf2f((u16)lv[j]);
    float4 h0 = *(const float4*)hp;
    float4 h1 = *(const float4*)(hp + 4);
    float hv[8] = {h0.x, h0.y, h0.z, h0.w, h1.x, h1.y, h1.z, h1.w};

    float m = lf[0];
    #pragma unroll
    for (int j = 1; j < 8; ++j) m = fmaxf(m, lf[j]);
    #pragma unroll
    for (int o = 32; o >= 1; o >>= 1) m = fmaxf(m, __shfl_xor(m, o));

    __shared__ float red[8];
    if (l == 0) red[w] = m;
    __syncthreads();
    m = fmaxf(fmaxf(red[0], red[1]), fmaxf(red[2], red[3]));
    __syncthreads();

    float se = 0.f, sh = 0.f;
    #pragma unroll
    for (int j = 0; j < 8; ++j) {
        float e = __expf(lf[j] - m);
        se += e;
        sh += e * hv[j];
    }
    #pragma unroll
    for (int o = 32; o >= 1; o >>= 1) { se += __shfl_xor(se, o); sh += __shfl_xor(sh, o); }
    if (l == 0) { red[w] = se; red[4 + w] = sh; }
    __syncthreads();
    if (t == 0) {
        float SE = red[0] + red[1] + red[2] + red[3];
        float SH = red[4] + red[5] + red[6] + red[7];
        float o = SH / SE;
        out[r] = o;
        out[R + r] = m_q[r & (D - 1)] + o;
    }
}

extern "C" void kernel_launch(void* const* d_in, const int* in_sizes, int n_in,
                              void* d_out, int out_size, void* d_ws, size_t ws_size,
                              hipStream_t stream) {
    const float* hidden = (const float*)d_in[0];
    const float* m_q    = (const float*)d_in[1];
    const float* Wq     = (const float*)d_in[2];
    const float* bq     = (const float*)d_in[3];
    const float* Wm     = (const float*)d_in[4];
    const float* bm     = (const float*)d_in[5];
    const float* Wa     = (const float*)d_in[6];
    const float* ba     = (const float*)d_in[7];
    float* out = (float*)d_out;

    const int D = 2048;
    const int M = 16 * 2048;  // B*S = 32768

    char* ws = (char*)d_ws;
    size_t oH  = 0;
    size_t oS  = oH  + (size_t)M * D * 2;   // Sg bf16
    size_t oWq = oS  + (size_t)M * D * 2;
    size_t oWa = oWq + (size_t)D * D * 2;
    size_t oMq = oWa + (size_t)D * D * 2;
    size_t need = oMq + (size_t)D * sizeof(float);
    if (ws_size < need) return;

    u16* hbf    = (u16*)(ws + oH);
    u16* Sg     = (u16*)(ws + oS);
    u16* Wqb    = (u16*)(ws + oWq);
    u16* Wab    = (u16*)(ws + oWa);
    float* mq   = (float*)(ws + oMq);
    u16* logits = hbf;  // alias: hidden_bf16 dead after GEMM1

    cvt_f32_bf16<<<4096, 256, 0, stream>>>(hidden, hbf, M * D / 8);
    cvt_f32_bf16<<<1024, 256, 0, stream>>>(Wq, Wqb, D * D / 8);
    cvt_f32_bf16<<<1024, 256, 0, stream>>>(Wa, Wab, D * D / 8);
    mq_kernel<<<D / 4, 256, 0, stream>>>(Wm, m_q, bm, mq, D);

    dim3 grid(D / 256, M / 256);  // (8, 128)
    gemm8<0><<<grid, 512, 0, stream>>>(hbf, Wqb, bq, mq, Sg, M, D, D);
    gemm8<1><<<grid, 512, 0, stream>>>(Sg, Wab, ba, nullptr, logits, M, D, D);

    softmax_out<<<M, 256, 0, stream>>>(logits, hidden, m_q, out, D, M);
}